// Round 10
// baseline (37.454 us; speedup 1.0000x reference)
//
#include <hip/hip_runtime.h>
#include <hip/hip_bf16.h>

// TiedCirculantSpectralFilter: B=512, D=1024, P=64, K=16, L_S=16
// Gram G[m,n] = sum_d X[d,m] * (gamma_d * X[d,n]) / 64  via bf16 MFMA,
// then 16 steps: hp <- hp - (1/16) A hp ; hk <- hk + (1/16) C hp.
//
// r9 winner + two scheduling changes (minimal deep-prefetch, r7 redone
// without the confounds):
//  - issue distance 2 chunks: two named register sets (A=even, B=odd chunks);
//    STAGE(q) drains only loads issued 2 iterations earlier (counted vmcnt),
//    removing the ~0.4us/chunk stall of the 1-iteration distance.
//  - single barrier per chunk: stage-before-MFMA makes the top barrier fence
//    both the staged buffer's visibility and the overwritten buffer's readers.

namespace {
typedef __attribute__((ext_vector_type(8))) short bf16x8;
typedef __attribute__((ext_vector_type(4))) float f32x4;
typedef __attribute__((ext_vector_type(4))) float fv4;
typedef __attribute__((ext_vector_type(2))) unsigned uv2;

constexpr int kB  = 512;
constexpr int kD  = 1024;
constexpr int kP  = 64;
constexpr int kKK = 16;
constexpr int kLS = 16;
constexpr int kThreads = 320;           // 5 waves
constexpr int kKc = 64;                 // d-rows per chunk
constexpr int kNC = kD / kKc;           // 16 chunks

constexpr int TB    = 4096;             // gamma f32[1024] at byte 0
constexpr int ASZ   = 80 * 128;         // A tile [80 m][64 k] bf16, swizzled
constexpr int BSZ   = 64 * 128;         // B tile [64 n][64 k] bf16, gamma-weighted
constexpr int BUFSZ = ASZ + BSZ;        // 18432
constexpr int LDS_BYTES = TB + 2 * BUFSZ;  // 40960
constexpr int GSTRIDE = 68;             // floats; 16B-aligned rows, odd bank stride

__device__ __forceinline__ unsigned bpack(float lo, float hi) {
  __hip_bfloat16 hl = __float2bfloat16(lo);
  __hip_bfloat16 hh = __float2bfloat16(hi);
  unsigned short ul, uh;
  __builtin_memcpy(&ul, &hl, 2);
  __builtin_memcpy(&uh, &hh, 2);
  return (unsigned)ul | ((unsigned)uh << 16);
}

#define ISSUE(q, S0, S1, S2, S3)                                    \
  { const int base_ = ((q) * kKc + 4 * kt) * 20 + ct;               \
    S0 = Xg[base_]; S1 = Xg[base_ + 20];                            \
    S2 = Xg[base_ + 40]; S3 = Xg[base_ + 60]; }

#define STAGE(q, S0, S1, S2, S3)                                    \
  { const fv4 g4_ = *reinterpret_cast<const fv4*>(gs + (q) * kKc + 4 * kt); \
    char* Ab_ = smem + TB + ((q) & 1) * BUFSZ;                      \
    char* Bb_ = Ab_ + ASZ;                                          \
    _Pragma("unroll")                                               \
    for (int j = 0; j < 4; ++j) {                                   \
      const int m_ = 4 * ct + j;                                    \
      const int off_ = m_ * 128 + ((8 * kt) ^ ((m_ & 7) << 4));     \
      uv2 wa; wa.x = bpack(S0[j], S1[j]); wa.y = bpack(S2[j], S3[j]); \
      *reinterpret_cast<uv2*>(Ab_ + off_) = wa;                     \
      if (ct < 16) {                                                \
        uv2 wb; wb.x = bpack(g4_[0] * S0[j], g4_[1] * S1[j]);       \
        wb.y = bpack(g4_[2] * S2[j], g4_[3] * S3[j]);               \
        *reinterpret_cast<uv2*>(Bb_ + off_) = wb;                   \
      }                                                             \
    } }

#define MFMA_STEP(BUFPAR)                                           \
  { const char* Ab_ = smem + TB + (BUFPAR) * BUFSZ;                 \
    const char* Bb_ = Ab_ + ASZ;                                    \
    _Pragma("unroll")                                               \
    for (int ks = 0; ks < 2; ++ks) {                                \
      const int cb_ = ks * 64 + colb;                               \
      const bf16x8 a_ = *reinterpret_cast<const bf16x8*>(           \
          Ab_ + rA * 128 + (cb_ ^ fswz));                           \
      _Pragma("unroll")                                             \
      for (int nt = 0; nt < 4; ++nt) {                              \
        const bf16x8 bb_ = *reinterpret_cast<const bf16x8*>(        \
            Bb_ + (16 * nt + (l & 15)) * 128 + (cb_ ^ fswz));       \
        acc[nt] = __builtin_amdgcn_mfma_f32_16x16x32_bf16(a_, bb_, acc[nt], 0, 0, 0); \
      }                                                             \
    } }

__global__ void __launch_bounds__(kThreads)
tcsf_kernel(const float* __restrict__ X, const float* __restrict__ y,
            const float* __restrict__ gamma, float* __restrict__ out) {
  __shared__ __align__(16) char smem[LDS_BYTES];
  float* gs = reinterpret_cast<float*>(smem);

  const int t = threadIdx.x;
  const int b = blockIdx.x;
  const int l = t & 63;
  const int w = t >> 6;            // wave 0..4 -> m-rows 16w..16w+15

  float yv = 0.f;
  if (t < kP) yv = y[b * kP + t];
  for (int i = t; i < kD; i += kThreads) gs[i] = gamma[i];

  const fv4* Xg = reinterpret_cast<const fv4*>(X) + (size_t)b * (kD * 80 / 4);

  // staging decomposition: thread t handles k = 4*kt + i (i=0..3), m = 4*ct + j
  const int ct = t % 20;           // m-quad
  const int kt = t / 20;           // k-quad (0..15)

  f32x4 acc[4];
#pragma unroll
  for (int nt = 0; nt < 4; ++nt) acc[nt] = (f32x4)(0.f);

  // two register load-sets: set A holds even chunks, set B odd chunks
  fv4 sA0, sA1, sA2, sA3;
  fv4 sB0, sB1, sB2, sB3;

  ISSUE(0, sA0, sA1, sA2, sA3);
  ISSUE(1, sB0, sB1, sB2, sB3);
  __syncthreads();  // gamma visible
  STAGE(0, sA0, sA1, sA2, sA3);          // drains chunk-0 loads only
  ISSUE(2, sA0, sA1, sA2, sA3);          // reuse freed set A

  // fragment read addressing (constant per thread)
  const int rA = 16 * w + (l & 15);
  const int colb = (l >> 4) * 16;
  const int fswz = (l & 7) << 4;   // rA&7 == l&7, rB&7 == l&7

  // ---- main loop: 1 barrier/chunk, issue distance 2 chunks ----
  for (int c = 0; c < kNC; c += 2) {
    // even body: chunk c
    __syncthreads();               // buf[c&1] visible; buf1's old readers done
    STAGE(c + 1, sB0, sB1, sB2, sB3);          // c+1 <= 15 always
    if (c + 3 < kNC) ISSUE(c + 3, sB0, sB1, sB2, sB3);
    MFMA_STEP(0);
    // odd body: chunk c+1
    __syncthreads();
    if (c + 2 < kNC) {
      STAGE(c + 2, sA0, sA1, sA2, sA3);
      if (c + 4 < kNC) ISSUE(c + 4, sA0, sA1, sA2, sA3);
    }
    MFMA_STEP(1);
  }
  __syncthreads();  // all MFMA reads done -> reuse tile LDS for G

  // ---- G -> LDS ----
  // C/D layout: col = lane&15, row = (lane>>4)*4 + reg
  float* Gl = reinterpret_cast<float*>(smem + TB);  // [80][GSTRIDE]
  float* hp = Gl + 80 * GSTRIDE;                    // [64]
  constexpr float invP = 1.0f / 64.0f;
#pragma unroll
  for (int nt = 0; nt < 4; ++nt)
#pragma unroll
    for (int r = 0; r < 4; ++r)
      Gl[(16 * w + (l >> 4) * 4 + r) * GSTRIDE + 16 * nt + (l & 15)] =
          acc[nt][r] * invP;

  if (t < kP) hp[t] = yv;
  __syncthreads();

  // ---- phase 2: 16 steps, 4 threads per row; G row in registers ----
  const int m = t >> 2;        // 0..79
  const int part = t & 3;
  const fv4* Grow4 = reinterpret_cast<const fv4*>(Gl + m * GSTRIDE + part * 16);
  const fv4* hpp4  = reinterpret_cast<const fv4*>(hp + part * 16);
  const fv4 G0 = Grow4[0], G1 = Grow4[1], G2 = Grow4[2], G3 = Grow4[3];
  float hk = 0.f;
  constexpr float invL = 1.0f / kLS;
  for (int s = 0; s < kLS; ++s) {
    const fv4 h0 = hpp4[0], h1 = hpp4[1], h2 = hpp4[2], h3 = hpp4[3];
    float d0 = 0.f, d1 = 0.f, d2 = 0.f, d3 = 0.f;
#pragma unroll
    for (int i = 0; i < 4; ++i) {
      d0 = fmaf(G0[i], h0[i], d0);
      d1 = fmaf(G1[i], h1[i], d1);
      d2 = fmaf(G2[i], h2[i], d2);
      d3 = fmaf(G3[i], h3[i], d3);
    }
    float dot = (d0 + d1) + (d2 + d3);
    dot += __shfl_xor(dot, 1);
    dot += __shfl_xor(dot, 2);
    __syncthreads();  // all reads of hp for this step complete
    if (part == 0) {
      if (m < kP) hp[m] -= invL * dot;   // unique writer per m
      else        hk   += invL * dot;
    }
    __syncthreads();  // hp update visible for next step
  }
  if (part == 0 && m >= kP) out[b * kKK + (m - kP)] = hk;
}

}  // namespace

extern "C" void kernel_launch(void* const* d_in, const int* in_sizes, int n_in,
                              void* d_out, int out_size, void* d_ws, size_t ws_size,
                              hipStream_t stream) {
  const float* X     = (const float*)d_in[0];  // [512,1024,80]
  const float* y     = (const float*)d_in[1];  // [512,64]
  const float* gamma = (const float*)d_in[2];  // [1024]
  float* out = (float*)d_out;                  // [512,16]
  tcsf_kernel<<<dim3(kB), dim3(kThreads), 0, stream>>>(X, y, gamma, out);
}